// Round 4
// baseline (154.930 us; speedup 1.0000x reference)
//
#include <hip/hip_runtime.h>

#define N_NODES 50000
#define N_EDGES 800000
#define D_FEAT  64

__device__ __forceinline__ float bf16_to_f(unsigned short h) {
    return __uint_as_float(((unsigned int)h) << 16);
}
__device__ __forceinline__ unsigned short f_to_bf16_rne(float f) {
    unsigned int u = __float_as_uint(f);
    u += 0x7fffu + ((u >> 16) & 1u);   // round-to-nearest-even
    return (unsigned short)(u >> 16);
}

// ---- Fused: x f32->bf16 convert + linked-list inversion of dst ------------
// N_NODES*16 float4-chunks == 800000 == N_EDGES, so every thread does one of
// each. rec[i] is written COALESCED (indexed by edge id); the only random
// traffic is the 200KB head[] atomics (L2-hot).
__global__ __launch_bounds__(256) void build_kernel(
    const float4* __restrict__ x4,     // [N*16]
    const float*  __restrict__ e,      // [E]
    const int*    __restrict__ src,    // [E]
    const int*    __restrict__ dst,    // [E]
    int*          __restrict__ head,   // [N], pre-inited to -1 (0xFF memset)
    int4*         __restrict__ rec,    // [E] {src, w_bits, next, pad}
    ushort4*      __restrict__ xb4)    // [N*16]
{
    int i = blockIdx.x * blockDim.x + threadIdx.x;

    if (i < N_NODES * (D_FEAT / 4)) {
        float4 v = x4[i];
        ushort4 h;
        h.x = f_to_bf16_rne(v.x); h.y = f_to_bf16_rne(v.y);
        h.z = f_to_bf16_rne(v.z); h.w = f_to_bf16_rne(v.w);
        xb4[i] = h;
    }

    if (i < N_EDGES) {
        int d   = dst[i];
        int old = atomicExch(&head[d], i);     // push edge i onto d's list
        rec[i]  = make_int4(src[i], __float_as_int(e[i]), old, 0);
    }
}

// ---- Reduce: 16-lane quarter per node; walk the chain ---------------------
// Per hop: one quarter-uniform 16B rec load (broadcast) + one 128B bf16 row
// gather (16 lanes x ushort4). fp32 accumulate. No atomics, no drops.
__global__ __launch_bounds__(256) void chain_reduce_kernel(
    const ushort4* __restrict__ xb4,    // [N*16]
    const int*     __restrict__ head,   // [N]
    const int4*    __restrict__ rec,    // [E]
    float4*        __restrict__ out4)   // [N*16]
{
    int lane   = threadIdx.x & 63;
    int waveId = (blockIdx.x * blockDim.x + threadIdx.x) >> 6;
    int p      = lane >> 4;             // quarter 0..3
    int sub    = lane & 15;             // column group within row
    int n      = waveId * 4 + p;        // node handled by this quarter
    if (n >= N_NODES) return;

    float4 acc = make_float4(0.f, 0.f, 0.f, 0.f);
    int eid = head[n];
    while (eid != -1) {
        int4  r = rec[eid];             // {src, w_bits, next, pad}
        float w = __int_as_float(r.y);
        ushort4 h = xb4[r.x * 16 + sub];
        acc.x += w * bf16_to_f(h.x);
        acc.y += w * bf16_to_f(h.y);
        acc.z += w * bf16_to_f(h.z);
        acc.w += w * bf16_to_f(h.w);
        eid = r.z;
    }

    out4[n * 16 + sub] = acc;           // 16 lanes x 16B = 256B per node
}

// ---- Fallback (ws too small): atomic scatter ------------------------------
__global__ __launch_bounds__(256) void scatter_add_kernel(
    const float* __restrict__ x,
    const float* __restrict__ e,
    const int*   __restrict__ src,
    const int*   __restrict__ dst,
    float*       __restrict__ out)
{
    long long idx = (long long)blockIdx.x * blockDim.x + threadIdx.x;
    if (idx >= (long long)N_EDGES * (D_FEAT / 4)) return;
    int edge = (int)(idx >> 4);
    int c    = (int)(idx & 15);
    int   s = src[edge];
    int   d = dst[edge];
    float w = e[edge];
    const float4* x4 = (const float4*)x;
    float4 v = x4[(long long)s * (D_FEAT / 4) + c];
    float* o = out + (long long)d * D_FEAT + c * 4;
    atomicAdd(o + 0, v.x * w);
    atomicAdd(o + 1, v.y * w);
    atomicAdd(o + 2, v.z * w);
    atomicAdd(o + 3, v.w * w);
}

extern "C" void kernel_launch(void* const* d_in, const int* in_sizes, int n_in,
                              void* d_out, int out_size, void* d_ws, size_t ws_size,
                              hipStream_t stream)
{
    // Inputs: t (scalar, unused), x [N,64] f32, e [E,1] f32, src [E] i32, dst [E] i32
    const float* x   = (const float*)d_in[1];
    const float* e   = (const float*)d_in[2];
    const int*   src = (const int*)d_in[3];
    const int*   dst = (const int*)d_in[4];
    float*       out = (float*)d_out;

    // Workspace: head [N] int | rec [E] int4 | xb [N*64] bf16
    size_t off_head = 0;
    size_t off_rec  = (off_head + (size_t)N_NODES * sizeof(int) + 15) & ~(size_t)15;
    size_t off_xb   = off_rec + (size_t)N_EDGES * sizeof(int4);
    size_t need     = off_xb + (size_t)N_NODES * D_FEAT * sizeof(unsigned short);

    if (ws_size >= need) {
        int*     head = (int*)((char*)d_ws + off_head);
        int4*    rec  = (int4*)((char*)d_ws + off_rec);
        ushort4* xb4  = (ushort4*)((char*)d_ws + off_xb);

        // head = -1 everywhere (0xFF bytes)
        hipMemsetAsync(head, 0xFF, (size_t)N_NODES * sizeof(int), stream);

        int block = 256;
        int gridB = (N_EDGES + block - 1) / block;              // 3125
        build_kernel<<<gridB, block, 0, stream>>>(
            (const float4*)x, e, src, dst, head, rec, xb4);

        // 4 nodes per wave, 4 waves per block -> 16 nodes/block
        int gridR = (N_NODES + 15) / 16;                        // 3125
        chain_reduce_kernel<<<gridR, block, 0, stream>>>(
            xb4, head, rec, (float4*)out);
    } else {
        hipMemsetAsync(out, 0, (size_t)out_size * sizeof(float), stream);
        long long total = (long long)N_EDGES * (D_FEAT / 4);
        int block = 256;
        int grid  = (int)((total + block - 1) / block);
        scatter_add_kernel<<<grid, block, 0, stream>>>(x, e, src, dst, out);
    }
}